// Round 1
// 817.185 us; speedup vs baseline: 1.0584x; 1.0584x over previous
//
#include <hip/hip_runtime.h>
#include <hip/hip_bf16.h>
#include <cstdint>
#include <type_traits>

#define DIM    4096
#define NHEADS 32
#define NKVH   8
#define HD     128
#define BATCH  2
#define SEQ    2048
#define MROWS  (BATCH*SEQ)      // 4096
#define NQKV   6144             // DIM + 2*NKVH*HD
#define KOFF   4096
#define VOFF   5120

typedef __attribute__((ext_vector_type(8))) __bf16 bf16x8;
typedef __attribute__((ext_vector_type(4))) __bf16 bf16x4;
typedef __attribute__((ext_vector_type(4))) float  f32x4;

// scale folded into Q: log2(e)/sqrt(HD) so softmax uses exp2 (native v_exp_f32)
#define QSCALE 0.1275174338f

__device__ __forceinline__ void gl_lds16(const __bf16* g, __bf16* l) {
    __builtin_amdgcn_global_load_lds(
        (const __attribute__((address_space(1))) void*)g,
        (__attribute__((address_space(3))) void*)l, 16, 0, 0);
}

// ---------------- fp32 -> bf16 cast (8 elem/thread) ----------------
__global__ void cast_f32_bf16(const float* __restrict__ s, __bf16* __restrict__ d, int n8) {
    int i = blockIdx.x * 256 + threadIdx.x;
    if (i >= n8) return;
    float4 a = ((const float4*)s)[2*i];
    float4 b = ((const float4*)s)[2*i+1];
    bf16x8 v;
    v[0]=(__bf16)a.x; v[1]=(__bf16)a.y; v[2]=(__bf16)a.z; v[3]=(__bf16)a.w;
    v[4]=(__bf16)b.x; v[5]=(__bf16)b.y; v[6]=(__bf16)b.z; v[7]=(__bf16)b.w;
    ((bf16x8*)d)[i] = v;
}

// ---------------- GEMM: C[m,n] = sum_k A[m,k]*B[n,k]  (both row-major, K contig) ----
// m97 structure + XOR-swizzled LDS (chunk ^= row&7) to kill 16-way read conflicts.
template<typename OutT>
__global__ __launch_bounds__(256)
void gemm_bt(const __bf16* __restrict__ A, const __bf16* __restrict__ Bm,
             OutT* __restrict__ C, int M, int N, int K,
             float scale, int scale_cols)
{
    __shared__ __bf16 As[128*64];
    __shared__ __bf16 Bs[128*64];
    const int tid  = threadIdx.x;
    const int lane = tid & 63;
    const int w    = tid >> 6;
    const int quad = lane >> 4;
    const int l16  = lane & 15;
    const int m0   = blockIdx.y * 128;
    const int n0   = blockIdx.x * 128;
    const int wm   = (w & 1) * 64;
    const int wn   = (w >> 1) * 64;

    const __bf16* Ab = A  + (size_t)m0 * K;
    const __bf16* Bb = Bm + (size_t)n0 * K;

    f32x4 acc[4][4] = {};

    for (int k0 = 0; k0 < K; k0 += 64) {
        __syncthreads();
        #pragma unroll
        for (int r = 0; r < 4; ++r) {
            int chunk = r*256 + tid;
            int row = chunk >> 3, c8 = chunk & 7;
            int c8s = c8 ^ (row & 7);                 // source-side swizzle
            gl_lds16(Ab + (size_t)row*K + k0 + c8s*8, As + chunk*8);
            gl_lds16(Bb + (size_t)row*K + k0 + c8s*8, Bs + chunk*8);
        }
        __syncthreads();
        #pragma unroll
        for (int t = 0; t < 2; ++t) {                 // kk = t*32
            bf16x8 af[4], bfr[4];
            #pragma unroll
            for (int i = 0; i < 4; ++i) {
                int row = wm + i*16 + l16;
                int cc  = (t*4 + quad) ^ (row & 7);
                af[i] = *(const bf16x8*)(As + row*64 + cc*8);
            }
            #pragma unroll
            for (int j = 0; j < 4; ++j) {
                int row = wn + j*16 + l16;
                int cc  = (t*4 + quad) ^ (row & 7);
                bfr[j] = *(const bf16x8*)(Bs + row*64 + cc*8);
            }
            #pragma unroll
            for (int i = 0; i < 4; ++i)
                #pragma unroll
                for (int j = 0; j < 4; ++j)
                    acc[i][j] = __builtin_amdgcn_mfma_f32_16x16x32_bf16(af[i], bfr[j], acc[i][j], 0,0,0);
        }
    }

    // C/D layout: col = lane&15, row = quad*4 + reg  [verified m89/m91]
    #pragma unroll
    for (int i = 0; i < 4; ++i) {
        #pragma unroll
        for (int j = 0; j < 4; ++j) {
            int col = n0 + wn + j*16 + l16;
            float sc = (col < scale_cols) ? scale : 1.0f;
            #pragma unroll
            for (int r = 0; r < 4; ++r) {
                int row = m0 + wm + i*16 + quad*4 + r;
                float v = acc[i][j][r] * sc;
                if constexpr (std::is_same<OutT, float>::value)
                    C[(size_t)row * N + col] = v;
                else
                    C[(size_t)row * N + col] = (__bf16)v;
            }
        }
    }
}

// ---------------- V transpose: vt[(b*8+g)*128 + d][s] = qkv[b*T+s][VOFF + g*128 + d] ----
__global__ void transpose_v(const __bf16* __restrict__ qkv, __bf16* __restrict__ vt) {
    int idx  = blockIdx.x * 256 + threadIdx.x;  // 524288 total
    int s8   = idx & 255;                        // T/8
    int rest = idx >> 8;                         // (b*8+g)*128 + d
    int d    = rest & (HD-1);
    int bg   = rest >> 7;
    int b    = bg >> 3;
    int g    = bg & 7;
    int s0   = s8 * 8;
    const __bf16* src = qkv + (size_t)(b*SEQ + s0)*NQKV + VOFF + g*HD + d;
    bf16x8 v;
    #pragma unroll
    for (int u = 0; u < 8; ++u) v[u] = src[(size_t)u*NQKV];
    *(bf16x8*)(vt + (size_t)rest*SEQ + s0) = v;
}

// ---------------- flash attention: S^T formulation, Q-tile 128, prefetch dbuf ----
// S^T = K·Q^T puts a whole q-row's scores in ONE lane (col=l16=q-row).
// 8 waves x 16 q-rows = 128-row Q tile: halves K/V staging traffic vs 64-row.
// T3 "minimum 2-phase": issue stage(next-tile) BEFORE compute(cur); the single
// __syncthreads() per tile drains vmcnt AFTER compute -> stage latency hidden.
// LDS: 2*16K (Ks) + 2*16K (Vts) + 16K (Ps) = 80 KB -> 2 blocks/CU (16 waves/CU).
__global__ __launch_bounds__(512, 4)
void flash_attn(const __bf16* __restrict__ qkv, const __bf16* __restrict__ vt,
                __bf16* __restrict__ O)
{
    __shared__ __bf16 Ks[2][64*128];   // [srow][d]   swizzled chunks
    __shared__ __bf16 Vts[2][128*64];  // [d][s]      swizzled chunks
    __shared__ __bf16 Ps[128*64];      // [qrow][s]   chunk-swizzled, per-wave rows

    const int qt = (gridDim.x - 1) - blockIdx.x;   // long blocks dispatch first
    const int bh = blockIdx.y;      // 0..63
    const int b  = bh >> 5;
    const int h  = bh & 31;
    const int g  = h >> 2;          // kv head (repeat_interleave)
    const int q0 = qt * 128;

    const int tid  = threadIdx.x;
    const int lane = tid & 63;
    const int w    = tid >> 6;      // 0..7
    const int quad = lane >> 4;
    const int l16  = lane & 15;
    const int psw  = (l16 & 7) << 1;   // Ps chunk swizzle (even -> keeps 16B pairs)

    const __bf16* Qb  = qkv + (size_t)(b*SEQ + q0)*NQKV + h*HD;
    const __bf16* Kb  = qkv + (size_t)(b*SEQ)*NQKV + KOFF + g*HD;
    const __bf16* Vtb = vt  + (size_t)((b*NKVH + g)*HD)*SEQ;

    // Q fragments in registers: wave w owns q-rows w*16..w*16+15 (lane's row = l16)
    bf16x8 qf[4];
    #pragma unroll
    for (int t = 0; t < 4; ++t)
        qf[t] = *(const bf16x8*)(Qb + (size_t)(w*16 + l16)*NQKV + t*32 + quad*8);

    f32x4 o_acc[8] = {};
    float m_i = -1e30f, l_i = 0.f;     // per-lane scalars: q-row = w*16 + l16
    const int myrow = q0 + w*16 + l16;
    const int wmin  = q0 + w*16;       // wave's lowest q-row

    const int nkt = 2*qt + 2;          // causal: K-tiles covering s <= q0+127

    // prologue: stage tile 0 into buffer 0 (latency exposed once per block)
    #pragma unroll
    for (int r = 0; r < 2; ++r) {
        int c = r*512 + tid;
        { int row = c >> 4, c16 = c & 15;
          int c16s = c16 ^ (row & 7);
          gl_lds16(Kb + (size_t)row*NQKV + c16s*8, &Ks[0][0] + c*8); }
        { int dd = c >> 3, c8 = c & 7;
          int c8s = c8 ^ (dd & 7);
          gl_lds16(Vtb + (size_t)dd*SEQ + c8s*8, &Vts[0][0] + c*8); }
    }
    __syncthreads();

    int cur = 0;
    for (int kt = 0; kt < nkt; ++kt) {
        const int s0 = kt * 64;

        // ---- issue next-tile stage (lands during compute; drained at barrier) ----
        if (kt + 1 < nkt) {
            const int sn = s0 + 64;
            __bf16* Ksb  = &Ks[cur^1][0];
            __bf16* Vtsb = &Vts[cur^1][0];
            #pragma unroll
            for (int r = 0; r < 2; ++r) {
                int c = r*512 + tid;
                { int row = c >> 4, c16 = c & 15;
                  int c16s = c16 ^ (row & 7);
                  gl_lds16(Kb + (size_t)(sn + row)*NQKV + c16s*8, Ksb + c*8); }
                { int dd = c >> 3, c8 = c & 7;
                  int c8s = c8 ^ (dd & 7);
                  gl_lds16(Vtb + (size_t)dd*SEQ + sn + c8s*8, Vtsb + c*8); }
            }
        }

        // ---- compute on current buffer (skip if tile fully above diagonal) ----
        if (s0 <= wmin + 15) {
            const __bf16* Ksb  = &Ks[cur][0];
            const __bf16* Vtsb = &Vts[cur][0];

            // S^T = K Q^T : C col = l16 = q-row, row = quad*4+r = s (within tile j)
            f32x4 s_acc[4] = {};
            #pragma unroll
            for (int t = 0; t < 4; ++t) {
                #pragma unroll
                for (int j = 0; j < 4; ++j) {
                    int row = j*16 + l16;
                    int cc  = (t*4 + quad) ^ (row & 7);
                    bf16x8 bk = *(const bf16x8*)(Ksb + row*128 + cc*8);
                    s_acc[j] = __builtin_amdgcn_mfma_f32_16x16x32_bf16(bk, qf[t], s_acc[j], 0,0,0);
                }
            }

            // causal mask on diagonal-crossing tiles (s = s0 + j*16 + quad*4 + r)
            if (s0 + 63 > wmin) {
                #pragma unroll
                for (int j = 0; j < 4; ++j)
                    #pragma unroll
                    for (int r = 0; r < 4; ++r)
                        if (s0 + j*16 + quad*4 + r > myrow) s_acc[j][r] = -1e30f;
            }

            // online softmax — in-lane over 16 regs, then 2 shfls across quads
            float pm = s_acc[0][0];
            #pragma unroll
            for (int j = 0; j < 4; ++j)
                #pragma unroll
                for (int r = 0; r < 4; ++r)
                    pm = fmaxf(pm, s_acc[j][r]);
            pm = fmaxf(pm, __shfl_xor(pm, 16));
            pm = fmaxf(pm, __shfl_xor(pm, 32));
            float mnew  = fmaxf(m_i, pm);
            float alpha = exp2f(m_i - mnew);
            m_i = mnew;

            float psum = 0.f;
            #pragma unroll
            for (int j = 0; j < 4; ++j) {
                bf16x4 pv;
                #pragma unroll
                for (int r = 0; r < 4; ++r) {
                    float p = exp2f(s_acc[j][r] - mnew);
                    psum += p;
                    pv[r] = (__bf16)p;
                }
                int cs = (j*4 + quad) ^ psw;
                *(bf16x4*)(Ps + (w*16 + l16)*64 + cs*4) = pv;   // ds_write_b64
            }
            psum += __shfl_xor(psum, 16);
            psum += __shfl_xor(psum, 32);
            l_i = l_i*alpha + psum;

            // broadcast alpha to O-rows (o_acc row = quad*4+r, alpha lives at lane l16=row)
            float av[4];
            #pragma unroll
            for (int r = 0; r < 4; ++r) av[r] = __shfl(alpha, quad*4 + r);
            #pragma unroll
            for (int jt = 0; jt < 8; ++jt)
                #pragma unroll
                for (int r = 0; r < 4; ++r)
                    o_acc[jt][r] *= av[r];

            // O += P V  (Ps rows are per-wave: no barrier needed, lgkmcnt suffices)
            #pragma unroll
            for (int t = 0; t < 2; ++t) {
                int cs = (t*8 + quad*2) ^ psw;
                bf16x8 ap = *(const bf16x8*)(Ps + (w*16 + l16)*64 + cs*4);
                #pragma unroll
                for (int jt = 0; jt < 8; ++jt) {
                    int row = jt*16 + l16;
                    int cc  = (t*4 + quad) ^ (row & 7);
                    bf16x8 bv = *(const bf16x8*)(Vtsb + row*64 + cc*8);
                    o_acc[jt] = __builtin_amdgcn_mfma_f32_16x16x32_bf16(ap, bv, o_acc[jt], 0,0,0);
                }
            }
        }

        // single barrier per tile: joins waves AND drains next-tile vmcnt
        // (issued one full compute-phase ago -> latency hidden)
        __syncthreads();
        cur ^= 1;
    }

    float inv = 1.0f / l_i;
    float ivr[4];
    #pragma unroll
    for (int r = 0; r < 4; ++r) ivr[r] = __shfl(inv, quad*4 + r);
    #pragma unroll
    for (int jt = 0; jt < 8; ++jt) {
        #pragma unroll
        for (int r = 0; r < 4; ++r) {
            int row = q0 + w*16 + quad*4 + r;
            int col = h*HD + jt*16 + l16;
            O[(size_t)(b*SEQ + row)*DIM + col] = (__bf16)(o_acc[jt][r] * ivr[r]);
        }
    }
}

extern "C" void kernel_launch(void* const* d_in, const int* in_sizes, int n_in,
                              void* d_out, int out_size, void* d_ws, size_t ws_size,
                              hipStream_t stream) {
    const float* x   = (const float*)d_in[0];
    const float* Wq  = (const float*)d_in[1];
    const float* Wkv = (const float*)d_in[2];
    const float* Wo  = (const float*)d_in[3];

    // workspace layout (bytes)
    const size_t OFF_XB   = 0;                       // 4096*4096 bf16 = 32 MB
    const size_t OFF_WQKV = 33554432;                // 6144*4096 bf16 = 48 MB
    const size_t OFF_WO   = 83886080;                // 4096*4096 bf16 = 32 MB
    const size_t OFF_QKV  = 117440512;               // 4096*6144 bf16 = 48 MB
    const size_t OFF_VT   = 167772160;               // 2*8*128*2048 bf16 = 8 MB
    const size_t OFF_OB   = 176160768;               // 4096*4096 bf16 = 32 MB
    const size_t NEEDED   = 209715200;               // 200 MB
    if (ws_size < NEEDED) return;

    char* ws = (char*)d_ws;
    __bf16* xb   = (__bf16*)(ws + OFF_XB);
    __bf16* wqkv = (__bf16*)(ws + OFF_WQKV);
    __bf16* wo   = (__bf16*)(ws + OFF_WO);
    __bf16* qkv  = (__bf16*)(ws + OFF_QKV);
    __bf16* vt   = (__bf16*)(ws + OFF_VT);
    __bf16* ob   = (__bf16*)(ws + OFF_OB);

    cast_f32_bf16<<<16777216/8/256, 256, 0, stream>>>(x,   xb,              16777216/8);
    cast_f32_bf16<<<16777216/8/256, 256, 0, stream>>>(Wq,  wqkv,            16777216/8);
    cast_f32_bf16<<< 8388608/8/256, 256, 0, stream>>>(Wkv, wqkv + 16777216,  8388608/8);
    cast_f32_bf16<<<16777216/8/256, 256, 0, stream>>>(Wo,  wo,              16777216/8);

    gemm_bt<__bf16><<<dim3(NQKV/128, MROWS/128), 256, 0, stream>>>(
        xb, wqkv, qkv, MROWS, NQKV, DIM, QSCALE, DIM);

    transpose_v<<<524288/256, 256, 0, stream>>>(qkv, vt);

    flash_attn<<<dim3(SEQ/128, BATCH*NHEADS), 512, 0, stream>>>(qkv, vt, ob);

    gemm_bt<float><<<dim3(DIM/128, MROWS/128), 256, 0, stream>>>(
        ob, wo, (float*)d_out, MROWS, DIM, DIM, 1.0f, 0);
}

// Round 2
// 809.692 us; speedup vs baseline: 1.0682x; 1.0093x over previous
//
#include <hip/hip_runtime.h>
#include <hip/hip_bf16.h>
#include <cstdint>
#include <type_traits>

#define DIM    4096
#define NHEADS 32
#define NKVH   8
#define HD     128
#define BATCH  2
#define SEQ    2048
#define MROWS  (BATCH*SEQ)      // 4096
#define NQKV   6144             // DIM + 2*NKVH*HD
#define KOFF   4096
#define VOFF   5120

typedef __attribute__((ext_vector_type(8))) __bf16 bf16x8;
typedef __attribute__((ext_vector_type(4))) __bf16 bf16x4;
typedef __attribute__((ext_vector_type(4))) float  f32x4;

// scale folded into Q: log2(e)/sqrt(HD) so softmax uses exp2 (native v_exp_f32)
#define QSCALE 0.1275174338f

__device__ __forceinline__ void gl_lds16(const __bf16* g, __bf16* l) {
    __builtin_amdgcn_global_load_lds(
        (const __attribute__((address_space(1))) void*)g,
        (__attribute__((address_space(3))) void*)l, 16, 0, 0);
}

// ---------------- fp32 -> bf16 cast (8 elem/thread) ----------------
__global__ void cast_f32_bf16(const float* __restrict__ s, __bf16* __restrict__ d, int n8) {
    int i = blockIdx.x * 256 + threadIdx.x;
    if (i >= n8) return;
    float4 a = ((const float4*)s)[2*i];
    float4 b = ((const float4*)s)[2*i+1];
    bf16x8 v;
    v[0]=(__bf16)a.x; v[1]=(__bf16)a.y; v[2]=(__bf16)a.z; v[3]=(__bf16)a.w;
    v[4]=(__bf16)b.x; v[5]=(__bf16)b.y; v[6]=(__bf16)b.z; v[7]=(__bf16)b.w;
    ((bf16x8*)d)[i] = v;
}

// ---------------- GEMM 256x256, 8-phase schedule (T2+T3+T4+T5 port) ----------------
// C[m,n] = sum_k A[m,k]*B[n,k], both row-major (K contiguous).
// 512 threads = 8 waves as 2(M)x4(N); per-wave output 128x64 = acc[8][4].
// K-tile = 64. LDS = 2 dbuf x (256x64 A + 256x64 B) bf16 = 128 KiB -> 1 block/CU.
// 4 phases per K-tile, each: {ds_read new frags | stage} RAW_BARRIER setprio(1)
// 16 MFMA (one C-quadrant x K=64) setprio(0) RAW_BARRIER.
// Staging for tile t+1 -> buf[cur^1] issued in phases 0-1 (>=2 clusters of slack);
// single vmcnt(0) + barrier + sched_barrier(0) at the K-tile boundary is the only
// correctness-bearing sync (producer->consumer per buffer; no WAR within a tile).
template<typename OutT>
__global__ __launch_bounds__(512, 2)
void gemm_bt256(const __bf16* __restrict__ A, const __bf16* __restrict__ Bm,
                OutT* __restrict__ C, int M, int N, int K,
                float scale, int scale_cols)
{
    __shared__ __bf16 As[2][256*64];
    __shared__ __bf16 Bs[2][256*64];

    // XCD-aware bijective swizzle on linearized block id (nwg % 8 == 0 at both call sites)
    const int nbx  = gridDim.x;
    const int nwg  = nbx * gridDim.y;
    const int orig = blockIdx.y * nbx + blockIdx.x;
    const int swz  = (orig & 7) * (nwg >> 3) + (orig >> 3);
    const int m0   = (swz / nbx) * 256;
    const int n0   = (swz % nbx) * 256;

    const int tid  = threadIdx.x;
    const int lane = tid & 63;
    const int w    = tid >> 6;          // 0..7
    const int quad = lane >> 4;
    const int l16  = lane & 15;
    const int wm   = (w >> 2) * 128;    // 0,128
    const int wn   = (w & 3)  * 64;     // 0,64,128,192

    const __bf16* Ab = A  + (size_t)m0 * K;
    const __bf16* Bb = Bm + (size_t)n0 * K;

    f32x4 acc[8][4] = {};

    auto stageA = [&](int buf, int k0) {
        #pragma unroll
        for (int i = 0; i < 4; ++i) {
            int chunk = i*512 + tid;
            int row = chunk >> 3, c8 = chunk & 7;
            int c8s = c8 ^ (row & 7);                 // source-side swizzle
            gl_lds16(Ab + (size_t)row*K + k0 + c8s*8, &As[buf][0] + chunk*8);
        }
    };
    auto stageB = [&](int buf, int k0) {
        #pragma unroll
        for (int i = 0; i < 4; ++i) {
            int chunk = i*512 + tid;
            int row = chunk >> 3, c8 = chunk & 7;
            int c8s = c8 ^ (row & 7);
            gl_lds16(Bb + (size_t)row*K + k0 + c8s*8, &Bs[buf][0] + chunk*8);
        }
    };

    // prologue: stage K-tile 0 (full drain once)
    stageA(0, 0); stageB(0, 0);
    asm volatile("s_waitcnt vmcnt(0)" ::: "memory");
    __builtin_amdgcn_s_barrier();
    __builtin_amdgcn_sched_barrier(0);

    const int NT = K >> 6;
    int cur = 0;
    for (int kt = 0; kt < NT; ++kt) {
        const int kn = (kt + 1) << 6;
        const __bf16* Ac = &As[cur][0];
        const __bf16* Bc = &Bs[cur][0];
        bf16x8 af[4][2], bfr[4][2];

        // ---- phase 0: read A rows 0-3 (8) + B cols 0-1 (4); stage next A ----
        #pragma unroll
        for (int i = 0; i < 4; ++i)
            #pragma unroll
            for (int t = 0; t < 2; ++t) {
                int row = wm + i*16 + l16;
                int cc  = (t*4 + quad) ^ (row & 7);
                af[i][t] = *(const bf16x8*)(Ac + row*64 + cc*8);
            }
        #pragma unroll
        for (int j = 0; j < 2; ++j)
            #pragma unroll
            for (int t = 0; t < 2; ++t) {
                int row = wn + j*16 + l16;
                int cc  = (t*4 + quad) ^ (row & 7);
                bfr[j][t] = *(const bf16x8*)(Bc + row*64 + cc*8);
            }
        if (kt + 1 < NT) stageA(cur ^ 1, kn);
        __builtin_amdgcn_s_barrier();
        __builtin_amdgcn_s_setprio(1);
        #pragma unroll
        for (int t = 0; t < 2; ++t)
            #pragma unroll
            for (int i = 0; i < 4; ++i)
                #pragma unroll
                for (int j = 0; j < 2; ++j)
                    acc[i][j] = __builtin_amdgcn_mfma_f32_16x16x32_bf16(af[i][t], bfr[j][t], acc[i][j], 0,0,0);
        __builtin_amdgcn_s_setprio(0);
        __builtin_amdgcn_s_barrier();

        // ---- phase 1: read B cols 2-3 (4); stage next B ----
        #pragma unroll
        for (int j = 2; j < 4; ++j)
            #pragma unroll
            for (int t = 0; t < 2; ++t) {
                int row = wn + j*16 + l16;
                int cc  = (t*4 + quad) ^ (row & 7);
                bfr[j][t] = *(const bf16x8*)(Bc + row*64 + cc*8);
            }
        if (kt + 1 < NT) stageB(cur ^ 1, kn);
        __builtin_amdgcn_s_barrier();
        __builtin_amdgcn_s_setprio(1);
        #pragma unroll
        for (int t = 0; t < 2; ++t)
            #pragma unroll
            for (int i = 0; i < 4; ++i)
                #pragma unroll
                for (int j = 2; j < 4; ++j)
                    acc[i][j] = __builtin_amdgcn_mfma_f32_16x16x32_bf16(af[i][t], bfr[j][t], acc[i][j], 0,0,0);
        __builtin_amdgcn_s_setprio(0);
        __builtin_amdgcn_s_barrier();

        // ---- phase 2: read A rows 4-7 (8, reuse af regs) ----
        #pragma unroll
        for (int i = 0; i < 4; ++i)
            #pragma unroll
            for (int t = 0; t < 2; ++t) {
                int row = wm + (4 + i)*16 + l16;
                int cc  = (t*4 + quad) ^ (row & 7);
                af[i][t] = *(const bf16x8*)(Ac + row*64 + cc*8);
            }
        __builtin_amdgcn_s_barrier();
        __builtin_amdgcn_s_setprio(1);
        #pragma unroll
        for (int t = 0; t < 2; ++t)
            #pragma unroll
            for (int i = 0; i < 4; ++i)
                #pragma unroll
                for (int j = 0; j < 2; ++j)
                    acc[4 + i][j] = __builtin_amdgcn_mfma_f32_16x16x32_bf16(af[i][t], bfr[j][t], acc[4 + i][j], 0,0,0);
        __builtin_amdgcn_s_setprio(0);
        __builtin_amdgcn_s_barrier();

        // ---- phase 3: no ds reads; MFMA; boundary drain ----
        __builtin_amdgcn_s_setprio(1);
        #pragma unroll
        for (int t = 0; t < 2; ++t)
            #pragma unroll
            for (int i = 0; i < 4; ++i)
                #pragma unroll
                for (int j = 2; j < 4; ++j)
                    acc[4 + i][j] = __builtin_amdgcn_mfma_f32_16x16x32_bf16(af[i][t], bfr[j][t], acc[4 + i][j], 0,0,0);
        __builtin_amdgcn_s_setprio(0);
        asm volatile("s_waitcnt vmcnt(0)" ::: "memory");   // next-tile stage complete
        __builtin_amdgcn_s_barrier();                       // all waves' drains done
        __builtin_amdgcn_sched_barrier(0);                  // pin: no hoist across handoff
        cur ^= 1;
    }

    // C/D layout: col = lane&15, row = quad*4 + reg  [verified m89/m91]
    #pragma unroll
    for (int i = 0; i < 8; ++i) {
        #pragma unroll
        for (int j = 0; j < 4; ++j) {
            int col = n0 + wn + j*16 + l16;
            float sc = (col < scale_cols) ? scale : 1.0f;
            #pragma unroll
            for (int r = 0; r < 4; ++r) {
                int row = m0 + wm + i*16 + quad*4 + r;
                float v = acc[i][j][r] * sc;
                if constexpr (std::is_same<OutT, float>::value)
                    C[(size_t)row * N + col] = v;
                else
                    C[(size_t)row * N + col] = (__bf16)v;
            }
        }
    }
}

// ---------------- V transpose: vt[(b*8+g)*128 + d][s] = qkv[b*T+s][VOFF + g*128 + d] ----
__global__ void transpose_v(const __bf16* __restrict__ qkv, __bf16* __restrict__ vt) {
    int idx  = blockIdx.x * 256 + threadIdx.x;  // 524288 total
    int s8   = idx & 255;                        // T/8
    int rest = idx >> 8;                         // (b*8+g)*128 + d
    int d    = rest & (HD-1);
    int bg   = rest >> 7;
    int b    = bg >> 3;
    int g    = bg & 7;
    int s0   = s8 * 8;
    const __bf16* src = qkv + (size_t)(b*SEQ + s0)*NQKV + VOFF + g*HD + d;
    bf16x8 v;
    #pragma unroll
    for (int u = 0; u < 8; ++u) v[u] = src[(size_t)u*NQKV];
    *(bf16x8*)(vt + (size_t)rest*SEQ + s0) = v;
}

// ---------------- flash attention: S^T formulation, Q-tile 128, prefetch dbuf ----
__global__ __launch_bounds__(512, 4)
void flash_attn(const __bf16* __restrict__ qkv, const __bf16* __restrict__ vt,
                __bf16* __restrict__ O)
{
    __shared__ __bf16 Ks[2][64*128];   // [srow][d]   swizzled chunks
    __shared__ __bf16 Vts[2][128*64];  // [d][s]      swizzled chunks
    __shared__ __bf16 Ps[128*64];      // [qrow][s]   chunk-swizzled, per-wave rows

    const int qt = (gridDim.x - 1) - blockIdx.x;   // long blocks dispatch first
    const int bh = blockIdx.y;      // 0..63
    const int b  = bh >> 5;
    const int h  = bh & 31;
    const int g  = h >> 2;          // kv head (repeat_interleave)
    const int q0 = qt * 128;

    const int tid  = threadIdx.x;
    const int lane = tid & 63;
    const int w    = tid >> 6;      // 0..7
    const int quad = lane >> 4;
    const int l16  = lane & 15;
    const int psw  = (l16 & 7) << 1;   // Ps chunk swizzle (even -> keeps 16B pairs)

    const __bf16* Qb  = qkv + (size_t)(b*SEQ + q0)*NQKV + h*HD;
    const __bf16* Kb  = qkv + (size_t)(b*SEQ)*NQKV + KOFF + g*HD;
    const __bf16* Vtb = vt  + (size_t)((b*NKVH + g)*HD)*SEQ;

    // Q fragments in registers: wave w owns q-rows w*16..w*16+15 (lane's row = l16)
    bf16x8 qf[4];
    #pragma unroll
    for (int t = 0; t < 4; ++t)
        qf[t] = *(const bf16x8*)(Qb + (size_t)(w*16 + l16)*NQKV + t*32 + quad*8);

    f32x4 o_acc[8] = {};
    float m_i = -1e30f, l_i = 0.f;     // per-lane scalars: q-row = w*16 + l16
    const int myrow = q0 + w*16 + l16;
    const int wmin  = q0 + w*16;       // wave's lowest q-row

    const int nkt = 2*qt + 2;          // causal: K-tiles covering s <= q0+127

    // prologue: stage tile 0 into buffer 0 (latency exposed once per block)
    #pragma unroll
    for (int r = 0; r < 2; ++r) {
        int c = r*512 + tid;
        { int row = c >> 4, c16 = c & 15;
          int c16s = c16 ^ (row & 7);
          gl_lds16(Kb + (size_t)row*NQKV + c16s*8, &Ks[0][0] + c*8); }
        { int dd = c >> 3, c8 = c & 7;
          int c8s = c8 ^ (dd & 7);
          gl_lds16(Vtb + (size_t)dd*SEQ + c8s*8, &Vts[0][0] + c*8); }
    }
    __syncthreads();

    int cur = 0;
    for (int kt = 0; kt < nkt; ++kt) {
        const int s0 = kt * 64;

        // ---- issue next-tile stage (lands during compute; drained at barrier) ----
        if (kt + 1 < nkt) {
            const int sn = s0 + 64;
            __bf16* Ksb  = &Ks[cur^1][0];
            __bf16* Vtsb = &Vts[cur^1][0];
            #pragma unroll
            for (int r = 0; r < 2; ++r) {
                int c = r*512 + tid;
                { int row = c >> 4, c16 = c & 15;
                  int c16s = c16 ^ (row & 7);
                  gl_lds16(Kb + (size_t)(sn + row)*NQKV + c16s*8, Ksb + c*8); }
                { int dd = c >> 3, c8 = c & 7;
                  int c8s = c8 ^ (dd & 7);
                  gl_lds16(Vtb + (size_t)dd*SEQ + sn + c8s*8, Vtsb + c*8); }
            }
        }

        // ---- compute on current buffer (skip if tile fully above diagonal) ----
        if (s0 <= wmin + 15) {
            const __bf16* Ksb  = &Ks[cur][0];
            const __bf16* Vtsb = &Vts[cur][0];

            // S^T = K Q^T : C col = l16 = q-row, row = quad*4+r = s (within tile j)
            f32x4 s_acc[4] = {};
            #pragma unroll
            for (int t = 0; t < 4; ++t) {
                #pragma unroll
                for (int j = 0; j < 4; ++j) {
                    int row = j*16 + l16;
                    int cc  = (t*4 + quad) ^ (row & 7);
                    bf16x8 bk = *(const bf16x8*)(Ksb + row*128 + cc*8);
                    s_acc[j] = __builtin_amdgcn_mfma_f32_16x16x32_bf16(bk, qf[t], s_acc[j], 0,0,0);
                }
            }

            // causal mask on diagonal-crossing tiles (s = s0 + j*16 + quad*4 + r)
            if (s0 + 63 > wmin) {
                #pragma unroll
                for (int j = 0; j < 4; ++j)
                    #pragma unroll
                    for (int r = 0; r < 4; ++r)
                        if (s0 + j*16 + quad*4 + r > myrow) s_acc[j][r] = -1e30f;
            }

            // online softmax — in-lane over 16 regs, then 2 shfls across quads
            float pm = s_acc[0][0];
            #pragma unroll
            for (int j = 0; j < 4; ++j)
                #pragma unroll
                for (int r = 0; r < 4; ++r)
                    pm = fmaxf(pm, s_acc[j][r]);
            pm = fmaxf(pm, __shfl_xor(pm, 16));
            pm = fmaxf(pm, __shfl_xor(pm, 32));
            float mnew  = fmaxf(m_i, pm);
            float alpha = exp2f(m_i - mnew);
            m_i = mnew;

            float psum = 0.f;
            #pragma unroll
            for (int j = 0; j < 4; ++j) {
                bf16x4 pv;
                #pragma unroll
                for (int r = 0; r < 4; ++r) {
                    float p = exp2f(s_acc[j][r] - mnew);
                    psum += p;
                    pv[r] = (__bf16)p;
                }
                int cs = (j*4 + quad) ^ psw;
                *(bf16x4*)(Ps + (w*16 + l16)*64 + cs*4) = pv;   // ds_write_b64
            }
            psum += __shfl_xor(psum, 16);
            psum += __shfl_xor(psum, 32);
            l_i = l_i*alpha + psum;

            // broadcast alpha to O-rows (o_acc row = quad*4+r, alpha lives at lane l16=row)
            float av[4];
            #pragma unroll
            for (int r = 0; r < 4; ++r) av[r] = __shfl(alpha, quad*4 + r);
            #pragma unroll
            for (int jt = 0; jt < 8; ++jt)
                #pragma unroll
                for (int r = 0; r < 4; ++r)
                    o_acc[jt][r] *= av[r];

            // O += P V  (Ps rows are per-wave: no barrier needed, lgkmcnt suffices)
            #pragma unroll
            for (int t = 0; t < 2; ++t) {
                int cs = (t*8 + quad*2) ^ psw;
                bf16x8 ap = *(const bf16x8*)(Ps + (w*16 + l16)*64 + cs*4);
                #pragma unroll
                for (int jt = 0; jt < 8; ++jt) {
                    int row = jt*16 + l16;
                    int cc  = (t*4 + quad) ^ (row & 7);
                    bf16x8 bv = *(const bf16x8*)(Vtsb + row*64 + cc*8);
                    o_acc[jt] = __builtin_amdgcn_mfma_f32_16x16x32_bf16(ap, bv, o_acc[jt], 0,0,0);
                }
            }
        }

        // single barrier per tile: joins waves AND drains next-tile vmcnt
        __syncthreads();
        cur ^= 1;
    }

    float inv = 1.0f / l_i;
    float ivr[4];
    #pragma unroll
    for (int r = 0; r < 4; ++r) ivr[r] = __shfl(inv, quad*4 + r);
    #pragma unroll
    for (int jt = 0; jt < 8; ++jt) {
        #pragma unroll
        for (int r = 0; r < 4; ++r) {
            int row = q0 + w*16 + quad*4 + r;
            int col = h*HD + jt*16 + l16;
            O[(size_t)(b*SEQ + row)*DIM + col] = (__bf16)(o_acc[jt][r] * ivr[r]);
        }
    }
}

extern "C" void kernel_launch(void* const* d_in, const int* in_sizes, int n_in,
                              void* d_out, int out_size, void* d_ws, size_t ws_size,
                              hipStream_t stream) {
    const float* x   = (const float*)d_in[0];
    const float* Wq  = (const float*)d_in[1];
    const float* Wkv = (const float*)d_in[2];
    const float* Wo  = (const float*)d_in[3];

    // workspace layout (bytes)
    const size_t OFF_XB   = 0;                       // 4096*4096 bf16 = 32 MB
    const size_t OFF_WQKV = 33554432;                // 6144*4096 bf16 = 48 MB
    const size_t OFF_WO   = 83886080;                // 4096*4096 bf16 = 32 MB
    const size_t OFF_QKV  = 117440512;               // 4096*6144 bf16 = 48 MB
    const size_t OFF_VT   = 167772160;               // 2*8*128*2048 bf16 = 8 MB
    const size_t OFF_OB   = 176160768;               // 4096*4096 bf16 = 32 MB
    const size_t NEEDED   = 209715200;               // 200 MB
    if (ws_size < NEEDED) return;

    char* ws = (char*)d_ws;
    __bf16* xb   = (__bf16*)(ws + OFF_XB);
    __bf16* wqkv = (__bf16*)(ws + OFF_WQKV);
    __bf16* wo   = (__bf16*)(ws + OFF_WO);
    __bf16* qkv  = (__bf16*)(ws + OFF_QKV);
    __bf16* vt   = (__bf16*)(ws + OFF_VT);
    __bf16* ob   = (__bf16*)(ws + OFF_OB);

    cast_f32_bf16<<<16777216/8/256, 256, 0, stream>>>(x,   xb,              16777216/8);
    cast_f32_bf16<<<16777216/8/256, 256, 0, stream>>>(Wq,  wqkv,            16777216/8);
    cast_f32_bf16<<< 8388608/8/256, 256, 0, stream>>>(Wkv, wqkv + 16777216,  8388608/8);
    cast_f32_bf16<<<16777216/8/256, 256, 0, stream>>>(Wo,  wo,              16777216/8);

    // 384 blocks (1.5 dispatch waves @1 block/CU) — expect ~75% tail efficiency
    gemm_bt256<__bf16><<<dim3(NQKV/256, MROWS/256), 512, 0, stream>>>(
        xb, wqkv, qkv, MROWS, NQKV, DIM, QSCALE, DIM);

    transpose_v<<<524288/256, 256, 0, stream>>>(qkv, vt);

    flash_attn<<<dim3(SEQ/128, BATCH*NHEADS), 512, 0, stream>>>(qkv, vt, ob);

    // 256 blocks — exactly one dispatch wave
    gemm_bt256<float><<<dim3(DIM/256, MROWS/256), 512, 0, stream>>>(
        ob, wo, (float*)d_out, MROWS, DIM, DIM, 1.0f, 0);
}